// Round 1
// baseline (306.197 us; speedup 1.0000x reference)
//
#include <hip/hip_runtime.h>

#define NTILES_X 65          // ceil(1026/16)
#define NTILES   (65*65)     // 4225
#define NBLK     1060        // grid for conv+gram; each block does 3-4 tiles
#define OHW      1026

// ---------------------------------------------------------------------------
// Kernel 1: fused conv1 (3->32, k3, pad2) + gram partial accumulation
// ---------------------------------------------------------------------------
__global__ __launch_bounds__(256) void k_conv_gram(
    const float* __restrict__ x,   // [3][1024][1024]
    const float* __restrict__ w1,  // [32][3][3][3]
    const float* __restrict__ b1,  // [32]
    float* __restrict__ partial)   // [NBLK][1024]
{
    __shared__ float sIn[3*18*18];   // input tile + halo (972 floats)
    __shared__ float sF[256*32];     // F[px][ch], slot-swizzled, 32 KB
    __shared__ float sGp[4*1024];    // per-wave gram partials (reused at end)

    const int t    = threadIdx.x;
    const int wv   = t >> 6;
    const int lane = t & 63;
    const int cblk = lane >> 3;   // 0..7 -> gram rows 4*cblk..+3
    const int dblk = lane & 7;    // 0..7 -> gram cols 4*dblk..+3

    float acc[4][4];
#pragma unroll
    for (int i = 0; i < 4; ++i)
#pragma unroll
        for (int j = 0; j < 4; ++j) acc[i][j] = 0.f;

    for (int tile = blockIdx.x; tile < NTILES; tile += NBLK) {
        const int ty = tile / NTILES_X;
        const int tx = tile - ty * NTILES_X;
        const int by = ty * 16, bx = tx * 16;

        // ---- stage input tile (18x18 per channel, zero-padded) ----
        for (int i = t; i < 972; i += 256) {
            int ic  = i / 324;
            int rem = i - ic * 324;
            int r   = rem / 18;
            int c   = rem - r * 18;
            int iy  = by - 2 + r;
            int ix  = bx - 2 + c;
            float v = 0.f;
            if ((unsigned)iy < 1024u && (unsigned)ix < 1024u)
                v = x[ic * 1048576 + iy * 1024 + ix];
            sIn[i] = v;
        }
        __syncthreads();

        // ---- conv: 1 px/thread, 32 output channels ----
        const int py = t >> 4, px = t & 15;
        float in[27];
#pragma unroll
        for (int ic = 0; ic < 3; ++ic)
#pragma unroll
            for (int ky = 0; ky < 3; ++ky)
#pragma unroll
                for (int kx = 0; kx < 3; ++kx)
                    in[ic*9 + ky*3 + kx] = sIn[ic*324 + (py+ky)*18 + (px+kx)];

        const bool valid = (by + py) < OHW && (bx + px) < OHW;
        const int slotx = t & 7;

        for (int oc4 = 0; oc4 < 8; ++oc4) {
            float a[4];
#pragma unroll
            for (int j = 0; j < 4; ++j) {
                const int oc = oc4 * 4 + j;
                float s = b1[oc];                       // uniform -> s_load
                const float* wr = w1 + oc * 27;        // uniform -> s_load
#pragma unroll
                for (int k = 0; k < 27; ++k) s = fmaf(in[k], wr[k], s);
                a[j] = valid ? s : 0.f;
            }
            // swizzled b128 store: F[p][oc4*4..+3] at slot (oc4 ^ (p&7))
            *(float4*)&sF[t * 32 + ((oc4 ^ slotx) << 2)] = *(float4*)a;
        }
        __syncthreads();

        // ---- gram accumulate: wave wv handles px [wv*64, wv*64+64) ----
        const int pbase = wv * 64;
#pragma unroll 8
        for (int pp = 0; pp < 64; ++pp) {
            const int p  = pbase + pp;
            const int sx = p & 7;
            float cf[4], df[4];
            *(float4*)cf = *(const float4*)&sF[p * 32 + ((cblk ^ sx) << 2)];
            *(float4*)df = *(const float4*)&sF[p * 32 + ((dblk ^ sx) << 2)];
#pragma unroll
            for (int i = 0; i < 4; ++i)
#pragma unroll
                for (int j = 0; j < 4; ++j)
                    acc[i][j] = fmaf(cf[i], df[j], acc[i][j]);
        }
        __syncthreads();   // protect sF/sIn for next iteration
    }

    // ---- cross-wave reduce (once per block) ----
#pragma unroll
    for (int i = 0; i < 4; ++i) {
        float tmp[4];
#pragma unroll
        for (int j = 0; j < 4; ++j) tmp[j] = acc[i][j];
        *(float4*)&sGp[wv * 1024 + (4*cblk + i) * 32 + 4*dblk] = *(float4*)tmp;
    }
    __syncthreads();
    {
        const int e = t * 4;
        float s[4] = {0.f, 0.f, 0.f, 0.f};
#pragma unroll
        for (int w = 0; w < 4; ++w) {
            float v[4];
            *(float4*)v = *(const float4*)&sGp[w * 1024 + e];
#pragma unroll
            for (int j = 0; j < 4; ++j) s[j] += v[j];
        }
        *(float4*)&partial[(size_t)blockIdx.x * 1024 + e] = *(float4*)s;
    }
}

// ---------------------------------------------------------------------------
// Kernel 2: reduce NBLK partials -> 16 partials (coalesced, deterministic)
// ---------------------------------------------------------------------------
__global__ __launch_bounds__(256) void k_reduce(
    const float* __restrict__ partial, float* __restrict__ partial2)
{
    const int gt    = blockIdx.x * 256 + threadIdx.x;  // 0..16383
    const int e     = gt & 1023;
    const int chunk = gt >> 10;                        // 0..15
    float s = 0.f;
    for (int b = chunk; b < NBLK; b += 16) s += partial[(size_t)b * 1024 + e];
    partial2[chunk * 1024 + e] = s;
}

// ---------------------------------------------------------------------------
// Kernel 3: tail — gram finalize + conv2+BN+ReLU + conv3+BN+ReLU + mean
// ---------------------------------------------------------------------------
__global__ __launch_bounds__(256) void k_tail(
    const float* __restrict__ partial2,
    const float* __restrict__ w2, const float* __restrict__ b2,
    const float* __restrict__ g2, const float* __restrict__ bt2,
    const float* __restrict__ w3, const float* __restrict__ b3,
    const float* __restrict__ g3, const float* __restrict__ bt3,
    float* __restrict__ out)
{
    __shared__ float G[1024];        // 32x32 gram
    __shared__ float y1[16 * 289];   // conv2 out / h1 (17x17)
    __shared__ float y2[32 * 100];   // conv3 out (10x10)
    __shared__ float m1[16], r1[16];

    const int t = threadIdx.x;

    // gram finalize
    {
        float s[4] = {0.f, 0.f, 0.f, 0.f};
        for (int k = 0; k < 16; ++k) {
            float v[4];
            *(float4*)v = *(const float4*)&partial2[k * 1024 + t * 4];
#pragma unroll
            for (int j = 0; j < 4; ++j) s[j] += v[j];
        }
        *(float4*)&G[t * 4] = *(float4*)s;
    }
    __syncthreads();

    // conv2: 1x32x32 -> 16x17x17, stride 2, pad 2
    for (int idx = t; idx < 16 * 289; idx += 256) {
        const int oc = idx / 289;
        const int r  = idx - oc * 289;
        const int oy = r / 17, ox = r - (r / 17) * 17;
        float s = b2[oc];
#pragma unroll
        for (int ky = 0; ky < 3; ++ky) {
            const int iy = 2 * oy + ky - 2;
            if ((unsigned)iy >= 32u) continue;
#pragma unroll
            for (int kx = 0; kx < 3; ++kx) {
                const int ix = 2 * ox + kx - 2;
                if ((unsigned)ix >= 32u) continue;
                s = fmaf(G[iy * 32 + ix], w2[oc * 9 + ky * 3 + kx], s);
            }
        }
        y1[idx] = s;
    }
    __syncthreads();

    // BN1 stats: 16 channels, 16 threads each
    {
        const int ch = t >> 4, j = t & 15;
        float s = 0.f, ss = 0.f;
        for (int i = j; i < 289; i += 16) {
            float v = y1[ch * 289 + i];
            s += v; ss += v * v;
        }
#pragma unroll
        for (int o = 8; o; o >>= 1) { s += __shfl_xor(s, o); ss += __shfl_xor(ss, o); }
        if (j == 0) {
            float m = s * (1.f / 289.f);
            float var = ss * (1.f / 289.f) - m * m;
            m1[ch] = m;
            r1[ch] = rsqrtf(var + 1e-5f);
        }
    }
    __syncthreads();

    // apply BN1 + ReLU in place
    for (int idx = t; idx < 16 * 289; idx += 256) {
        const int oc = idx / 289;
        float v = (y1[idx] - m1[oc]) * r1[oc] * g2[oc] + bt2[oc];
        y1[idx] = v > 0.f ? v : 0.f;
    }
    __syncthreads();

    // conv3: 16x17x17 -> 32x10x10, stride 2, pad 2
    for (int idx = t; idx < 3200; idx += 256) {
        const int oc = idx / 100;
        const int r  = idx - oc * 100;
        const int oy = r / 10, ox = r - (r / 10) * 10;
        float s = b3[oc];
        for (int ic = 0; ic < 16; ++ic) {
            const float* yi = y1 + ic * 289;
            const float* wr = w3 + (oc * 16 + ic) * 9;
#pragma unroll
            for (int ky = 0; ky < 3; ++ky) {
                const int iy = 2 * oy + ky - 2;
                if ((unsigned)iy >= 17u) continue;
#pragma unroll
                for (int kx = 0; kx < 3; ++kx) {
                    const int ix = 2 * ox + kx - 2;
                    if ((unsigned)ix >= 17u) continue;
                    s = fmaf(yi[iy * 17 + ix], wr[ky * 3 + kx], s);
                }
            }
        }
        y2[idx] = s;
    }
    __syncthreads();

    // BN2 + ReLU + spatial mean: 32 channels, 8 threads each
    {
        const int ch = t >> 3, j = t & 7;
        float s = 0.f, ss = 0.f;
        for (int i = j; i < 100; i += 8) {
            float v = y2[ch * 100 + i];
            s += v; ss += v * v;
        }
#pragma unroll
        for (int o = 4; o; o >>= 1) { s += __shfl_xor(s, o); ss += __shfl_xor(ss, o); }
        const float m  = s * 0.01f;
        const float var = ss * 0.01f - m * m;
        const float rs = rsqrtf(var + 1e-5f);
        float a = 0.f;
        for (int i = j; i < 100; i += 8) {
            float v = (y2[ch * 100 + i] - m) * rs * g3[ch] + bt3[ch];
            a += v > 0.f ? v : 0.f;
        }
#pragma unroll
        for (int o = 4; o; o >>= 1) a += __shfl_xor(a, o);
        if (j == 0) out[ch] = a * 0.01f;
    }
}

// ---------------------------------------------------------------------------
extern "C" void kernel_launch(void* const* d_in, const int* in_sizes, int n_in,
                              void* d_out, int out_size, void* d_ws, size_t ws_size,
                              hipStream_t stream)
{
    const float* x   = (const float*)d_in[0];
    const float* w1  = (const float*)d_in[1];
    const float* b1  = (const float*)d_in[2];
    const float* w2  = (const float*)d_in[3];
    const float* b2  = (const float*)d_in[4];
    const float* g2  = (const float*)d_in[5];
    const float* bt2 = (const float*)d_in[6];
    const float* w3  = (const float*)d_in[7];
    const float* b3  = (const float*)d_in[8];
    const float* g3  = (const float*)d_in[9];
    const float* bt3 = (const float*)d_in[10];

    float* P   = (float*)d_ws;                 // [NBLK][1024]
    float* P2  = P + (size_t)NBLK * 1024;      // [16][1024]
    float* out = (float*)d_out;                // 32 floats

    k_conv_gram<<<NBLK, 256, 0, stream>>>(x, w1, b1, P);
    k_reduce<<<64, 256, 0, stream>>>(P, P2);
    k_tail<<<1, 256, 0, stream>>>(P2, w2, b2, g2, bt2, w3, b3, g3, bt3, out);
}

// Round 2
// 265.765 us; speedup vs baseline: 1.1521x; 1.1521x over previous
//
#include <hip/hip_runtime.h>

#define NTILES_X 65          // ceil(1026/16)
#define NTILES   (65*65)     // 4225
#define OHW      1026
#define NCHUNK   32

// ---------------------------------------------------------------------------
// Kernel 1: fused conv1 (3->32, k3, pad2) + gram partial accumulation
// ---------------------------------------------------------------------------
__global__ __launch_bounds__(256, 4) void k_conv_gram(
    const float* __restrict__ x,   // [3][1024][1024]
    const float* __restrict__ w1,  // [32][3][3][3]
    const float* __restrict__ b1,  // [32]
    float* __restrict__ partial,   // [nblk][1024]
    int nblk)
{
    __shared__ float sIn[3*18*18];   // input tile + halo (972 floats)
    __shared__ float sF[256*32];     // F[px][ch] slot-swizzled (32 KB); aliased as gram partials

    const int t    = threadIdx.x;
    const int cblk = (t & 31) >> 2;   // 0..7 -> gram rows 4*cblk..+3
    const int db   = t & 3;           // 0..3 -> gram cols 8*db..+7
    const int pbase = (t >> 5) * 32;  // (wv*2+hw)*32 : 32 pixels per half-wave

    float acc[4][8];
#pragma unroll
    for (int i = 0; i < 4; ++i)
#pragma unroll
        for (int j = 0; j < 8; ++j) acc[i][j] = 0.f;

    for (int tile = blockIdx.x; tile < NTILES; tile += nblk) {
        const int ty = tile / NTILES_X;
        const int tx = tile - ty * NTILES_X;
        const int by = ty * 16, bx = tx * 16;
        const bool interior = (ty >= 1) & (ty <= 62) & (tx >= 1) & (tx <= 62);

        // ---- stage input tile (18x18 per channel) ----
        if (interior) {
            for (int i = t; i < 972; i += 256) {
                int ic  = i / 324;
                int rem = i - ic * 324;
                int r   = rem / 18;
                int c   = rem - r * 18;
                sIn[i] = x[ic * 1048576 + (by - 2 + r) * 1024 + (bx - 2 + c)];
            }
        } else {
            for (int i = t; i < 972; i += 256) {
                int ic  = i / 324;
                int rem = i - ic * 324;
                int r   = rem / 18;
                int c   = rem - r * 18;
                int iy  = by - 2 + r;
                int ix  = bx - 2 + c;
                float v = 0.f;
                if ((unsigned)iy < 1024u && (unsigned)ix < 1024u)
                    v = x[ic * 1048576 + iy * 1024 + ix];
                sIn[i] = v;
            }
        }
        __syncthreads();

        // ---- conv: 1 px/thread, 32 output channels ----
        const int py = t >> 4, px = t & 15;
        float in[27];
#pragma unroll
        for (int ic = 0; ic < 3; ++ic)
#pragma unroll
            for (int ky = 0; ky < 3; ++ky)
#pragma unroll
                for (int kx = 0; kx < 3; ++kx)
                    in[ic*9 + ky*3 + kx] = sIn[ic*324 + (py+ky)*18 + (px+kx)];

        const int slotx = t & 7;
        if (interior) {
            for (int oc4 = 0; oc4 < 8; ++oc4) {
                float a[4];
#pragma unroll
                for (int j = 0; j < 4; ++j) {
                    const int oc = oc4 * 4 + j;
                    float s = b1[oc];
                    const float* wr = w1 + oc * 27;
#pragma unroll
                    for (int k = 0; k < 27; ++k) s = fmaf(in[k], wr[k], s);
                    a[j] = s;
                }
                *(float4*)&sF[t * 32 + ((oc4 ^ slotx) << 2)] = *(float4*)a;
            }
        } else {
            const bool valid = (by + py) < OHW && (bx + px) < OHW;
            for (int oc4 = 0; oc4 < 8; ++oc4) {
                float a[4];
#pragma unroll
                for (int j = 0; j < 4; ++j) {
                    const int oc = oc4 * 4 + j;
                    float s = b1[oc];
                    const float* wr = w1 + oc * 27;
#pragma unroll
                    for (int k = 0; k < 27; ++k) s = fmaf(in[k], wr[k], s);
                    a[j] = valid ? s : 0.f;
                }
                *(float4*)&sF[t * 32 + ((oc4 ^ slotx) << 2)] = *(float4*)a;
            }
        }
        __syncthreads();

        // ---- gram accumulate: half-wave processes 32 pixels, 4x8 per lane ----
        {
            const float* fb = &sF[pbase * 32];
#pragma unroll
            for (int p8 = 0; p8 < 4; ++p8) {
#pragma unroll
                for (int k = 0; k < 8; ++k) {
                    const int po = (p8 * 8 + k) * 32;
                    float cf[4], d[8];
                    *(float4*)&cf[0] = *(const float4*)&fb[po + ((cblk ^ k) << 2)];
                    *(float4*)&d[0]  = *(const float4*)&fb[po + (((2*db) ^ k) << 2)];
                    *(float4*)&d[4]  = *(const float4*)&fb[po + (((2*db+1) ^ k) << 2)];
#pragma unroll
                    for (int i = 0; i < 4; ++i)
#pragma unroll
                        for (int j = 0; j < 8; ++j)
                            acc[i][j] = fmaf(cf[i], d[j], acc[i][j]);
                }
            }
        }
        __syncthreads();   // protect sF/sIn for next iteration
    }

    // ---- cross-(wave,half) reduce, once per block; alias sGp onto sF ----
    {
        float* gp = sF + (t >> 5) * 1024 + (4 * cblk) * 32 + 8 * db;
#pragma unroll
        for (int i = 0; i < 4; ++i) {
            float t0[4], t1[4];
#pragma unroll
            for (int j = 0; j < 4; ++j) { t0[j] = acc[i][j]; t1[j] = acc[i][j+4]; }
            *(float4*)&gp[i * 32]     = *(float4*)t0;
            *(float4*)&gp[i * 32 + 4] = *(float4*)t1;
        }
    }
    __syncthreads();
    {
        const int e = t * 4;
        float s[4] = {0.f, 0.f, 0.f, 0.f};
#pragma unroll
        for (int w = 0; w < 8; ++w) {
            float v[4];
            *(float4*)v = *(const float4*)&sF[w * 1024 + e];
#pragma unroll
            for (int j = 0; j < 4; ++j) s[j] += v[j];
        }
        *(float4*)&partial[(size_t)blockIdx.x * 1024 + e] = *(float4*)s;
    }
}

// ---------------------------------------------------------------------------
// Kernel 2: reduce nblk partials -> NCHUNK partials (coalesced)
// ---------------------------------------------------------------------------
__global__ __launch_bounds__(256) void k_reduce(
    const float* __restrict__ partial, float* __restrict__ partial2, int nblk)
{
    const int gt    = blockIdx.x * 256 + threadIdx.x;  // 0..32767
    const int e     = gt & 1023;
    const int chunk = gt >> 10;                        // 0..31
    float s = 0.f;
    for (int b = chunk; b < nblk; b += NCHUNK) s += partial[(size_t)b * 1024 + e];
    partial2[chunk * 1024 + e] = s;
}

// ---------------------------------------------------------------------------
// Kernel 3: tail — gram finalize + conv2+BN+ReLU + conv3+BN+ReLU + mean
// ---------------------------------------------------------------------------
__global__ __launch_bounds__(256) void k_tail(
    const float* __restrict__ partial2,
    const float* __restrict__ w2, const float* __restrict__ b2,
    const float* __restrict__ g2, const float* __restrict__ bt2,
    const float* __restrict__ w3, const float* __restrict__ b3,
    const float* __restrict__ g3, const float* __restrict__ bt3,
    float* __restrict__ out)
{
    __shared__ float G[1024];        // 32x32 gram
    __shared__ float y1[16 * 289];   // conv2 out / h1 (17x17)
    __shared__ float y2[32 * 100];   // conv3 out (10x10)
    __shared__ float m1[16], r1[16];

    const int t = threadIdx.x;

    // gram finalize
    {
        float s[4] = {0.f, 0.f, 0.f, 0.f};
        for (int k = 0; k < NCHUNK; ++k) {
            float v[4];
            *(float4*)v = *(const float4*)&partial2[k * 1024 + t * 4];
#pragma unroll
            for (int j = 0; j < 4; ++j) s[j] += v[j];
        }
        *(float4*)&G[t * 4] = *(float4*)s;
    }
    __syncthreads();

    // conv2: 1x32x32 -> 16x17x17, stride 2, pad 2
    for (int idx = t; idx < 16 * 289; idx += 256) {
        const int oc = idx / 289;
        const int r  = idx - oc * 289;
        const int oy = r / 17, ox = r - (r / 17) * 17;
        float s = b2[oc];
#pragma unroll
        for (int ky = 0; ky < 3; ++ky) {
            const int iy = 2 * oy + ky - 2;
            if ((unsigned)iy >= 32u) continue;
#pragma unroll
            for (int kx = 0; kx < 3; ++kx) {
                const int ix = 2 * ox + kx - 2;
                if ((unsigned)ix >= 32u) continue;
                s = fmaf(G[iy * 32 + ix], w2[oc * 9 + ky * 3 + kx], s);
            }
        }
        y1[idx] = s;
    }
    __syncthreads();

    // BN1 stats: 16 channels, 16 threads each
    {
        const int ch = t >> 4, j = t & 15;
        float s = 0.f, ss = 0.f;
        for (int i = j; i < 289; i += 16) {
            float v = y1[ch * 289 + i];
            s += v; ss += v * v;
        }
#pragma unroll
        for (int o = 8; o; o >>= 1) { s += __shfl_xor(s, o); ss += __shfl_xor(ss, o); }
        if (j == 0) {
            float m = s * (1.f / 289.f);
            float var = ss * (1.f / 289.f) - m * m;
            m1[ch] = m;
            r1[ch] = rsqrtf(var + 1e-5f);
        }
    }
    __syncthreads();

    // apply BN1 + ReLU in place
    for (int idx = t; idx < 16 * 289; idx += 256) {
        const int oc = idx / 289;
        float v = (y1[idx] - m1[oc]) * r1[oc] * g2[oc] + bt2[oc];
        y1[idx] = v > 0.f ? v : 0.f;
    }
    __syncthreads();

    // conv3: 16x17x17 -> 32x10x10, stride 2, pad 2
    for (int idx = t; idx < 3200; idx += 256) {
        const int oc = idx / 100;
        const int r  = idx - oc * 100;
        const int oy = r / 10, ox = r - (r / 10) * 10;
        float s = b3[oc];
        for (int ic = 0; ic < 16; ++ic) {
            const float* yi = y1 + ic * 289;
            const float* wr = w3 + (oc * 16 + ic) * 9;
#pragma unroll
            for (int ky = 0; ky < 3; ++ky) {
                const int iy = 2 * oy + ky - 2;
                if ((unsigned)iy >= 17u) continue;
#pragma unroll
                for (int kx = 0; kx < 3; ++kx) {
                    const int ix = 2 * ox + kx - 2;
                    if ((unsigned)ix >= 17u) continue;
                    s = fmaf(yi[iy * 17 + ix], wr[ky * 3 + kx], s);
                }
            }
        }
        y2[idx] = s;
    }
    __syncthreads();

    // BN2 + ReLU + spatial mean: 32 channels, 8 threads each
    {
        const int ch = t >> 3, j = t & 7;
        float s = 0.f, ss = 0.f;
        for (int i = j; i < 100; i += 8) {
            float v = y2[ch * 100 + i];
            s += v; ss += v * v;
        }
#pragma unroll
        for (int o = 4; o; o >>= 1) { s += __shfl_xor(s, o); ss += __shfl_xor(ss, o); }
        const float m  = s * 0.01f;
        const float var = ss * 0.01f - m * m;
        const float rs = rsqrtf(var + 1e-5f);
        float a = 0.f;
        for (int i = j; i < 100; i += 8) {
            float v = (y2[ch * 100 + i] - m) * rs * g3[ch] + bt3[ch];
            a += v > 0.f ? v : 0.f;
        }
#pragma unroll
        for (int o = 4; o; o >>= 1) a += __shfl_xor(a, o);
        if (j == 0) out[ch] = a * 0.01f;
    }
}

// ---------------------------------------------------------------------------
extern "C" void kernel_launch(void* const* d_in, const int* in_sizes, int n_in,
                              void* d_out, int out_size, void* d_ws, size_t ws_size,
                              hipStream_t stream)
{
    const float* x   = (const float*)d_in[0];
    const float* w1  = (const float*)d_in[1];
    const float* b1  = (const float*)d_in[2];
    const float* w2  = (const float*)d_in[3];
    const float* b2  = (const float*)d_in[4];
    const float* g2  = (const float*)d_in[5];
    const float* bt2 = (const float*)d_in[6];
    const float* w3  = (const float*)d_in[7];
    const float* b3  = (const float*)d_in[8];
    const float* g3  = (const float*)d_in[9];
    const float* bt3 = (const float*)d_in[10];

    // size grid from workspace: nblk partial grams (4 KB each) + NCHUNK stage-2
    size_t cap = ws_size / 4096;
    int nblk = (cap > (size_t)(NTILES + NCHUNK)) ? NTILES : (int)cap - NCHUNK;
    if (nblk > NTILES) nblk = NTILES;
    if (nblk < 256) nblk = 256;   // ws is known to hold at least this (R1 ran 1060)

    float* P   = (float*)d_ws;                 // [nblk][1024]
    float* P2  = P + (size_t)nblk * 1024;      // [NCHUNK][1024]
    float* out = (float*)d_out;                // 32 floats

    k_conv_gram<<<nblk, 256, 0, stream>>>(x, w1, b1, P, nblk);
    k_reduce<<<128, 256, 0, stream>>>(P, P2, nblk);
    k_tail<<<1, 256, 0, stream>>>(P2, w2, b2, g2, bt2, w3, b3, g3, bt3, out);
}

// Round 3
// 150.816 us; speedup vs baseline: 2.0303x; 1.7622x over previous
//
#include <hip/hip_runtime.h>

#define NTILES_X 65          // ceil(1026/16)
#define NTILES   (65*65)     // 4225
#define OHW      1026
#define NCHUNK   32

// ---------------------------------------------------------------------------
// Kernel 1: fused conv1 (3->32, k3, pad2) + gram partial accumulation
// ---------------------------------------------------------------------------
__global__ __launch_bounds__(256, 4) void k_conv_gram(
    const float* __restrict__ x,   // [3][1024][1024]
    const float* __restrict__ w1,  // [32][3][3][3]
    const float* __restrict__ b1,  // [32]
    float* __restrict__ partial,   // [nblk][1024]
    int nblk)
{
    __shared__ float sIn[3*18*18];   // input tile + halo (972 floats)
    __shared__ float sF[256*32];     // F[px][ch] slot-swizzled (32 KB); aliased as gram partials

    const int t    = threadIdx.x;
    const int cblk = (t & 31) >> 2;   // 0..7 -> gram rows 4*cblk..+3
    const int db   = t & 3;           // 0..3 -> gram cols 8*db..+7
    const int pbase = (t >> 5) * 32;  // (wv*2+hw)*32 : 32 pixels per half-wave

    float acc[4][8];
#pragma unroll
    for (int i = 0; i < 4; ++i)
#pragma unroll
        for (int j = 0; j < 8; ++j) acc[i][j] = 0.f;

    for (int tile = blockIdx.x; tile < NTILES; tile += nblk) {
        const int ty = tile / NTILES_X;
        const int tx = tile - ty * NTILES_X;
        const int by = ty * 16, bx = tx * 16;
        const bool interior = (ty >= 1) & (ty <= 62) & (tx >= 1) & (tx <= 62);

        // ---- stage input tile (18x18 per channel) ----
        if (interior) {
            for (int i = t; i < 972; i += 256) {
                int ic  = i / 324;
                int rem = i - ic * 324;
                int r   = rem / 18;
                int c   = rem - r * 18;
                sIn[i] = x[ic * 1048576 + (by - 2 + r) * 1024 + (bx - 2 + c)];
            }
        } else {
            for (int i = t; i < 972; i += 256) {
                int ic  = i / 324;
                int rem = i - ic * 324;
                int r   = rem / 18;
                int c   = rem - r * 18;
                int iy  = by - 2 + r;
                int ix  = bx - 2 + c;
                float v = 0.f;
                if ((unsigned)iy < 1024u && (unsigned)ix < 1024u)
                    v = x[ic * 1048576 + iy * 1024 + ix];
                sIn[i] = v;
            }
        }
        __syncthreads();

        // ---- conv: 1 px/thread, 32 output channels ----
        const int py = t >> 4, px = t & 15;
        float in[27];
#pragma unroll
        for (int ic = 0; ic < 3; ++ic)
#pragma unroll
            for (int ky = 0; ky < 3; ++ky)
#pragma unroll
                for (int kx = 0; kx < 3; ++kx)
                    in[ic*9 + ky*3 + kx] = sIn[ic*324 + (py+ky)*18 + (px+kx)];

        const int slotx = t & 7;
        if (interior) {
            for (int oc4 = 0; oc4 < 8; ++oc4) {
                float a[4];
#pragma unroll
                for (int j = 0; j < 4; ++j) {
                    const int oc = oc4 * 4 + j;
                    float s = b1[oc];
                    const float* wr = w1 + oc * 27;
#pragma unroll
                    for (int k = 0; k < 27; ++k) s = fmaf(in[k], wr[k], s);
                    a[j] = s;
                }
                *(float4*)&sF[t * 32 + ((oc4 ^ slotx) << 2)] = *(float4*)a;
            }
        } else {
            const bool valid = (by + py) < OHW && (bx + px) < OHW;
            for (int oc4 = 0; oc4 < 8; ++oc4) {
                float a[4];
#pragma unroll
                for (int j = 0; j < 4; ++j) {
                    const int oc = oc4 * 4 + j;
                    float s = b1[oc];
                    const float* wr = w1 + oc * 27;
#pragma unroll
                    for (int k = 0; k < 27; ++k) s = fmaf(in[k], wr[k], s);
                    a[j] = valid ? s : 0.f;
                }
                *(float4*)&sF[t * 32 + ((oc4 ^ slotx) << 2)] = *(float4*)a;
            }
        }
        __syncthreads();

        // ---- gram accumulate: half-wave processes 32 pixels, 4x8 per lane ----
        {
            const float* fb = &sF[pbase * 32];
#pragma unroll
            for (int p8 = 0; p8 < 4; ++p8) {
#pragma unroll
                for (int k = 0; k < 8; ++k) {
                    const int po = (p8 * 8 + k) * 32;
                    float cf[4], d[8];
                    *(float4*)&cf[0] = *(const float4*)&fb[po + ((cblk ^ k) << 2)];
                    *(float4*)&d[0]  = *(const float4*)&fb[po + (((2*db) ^ k) << 2)];
                    *(float4*)&d[4]  = *(const float4*)&fb[po + (((2*db+1) ^ k) << 2)];
#pragma unroll
                    for (int i = 0; i < 4; ++i)
#pragma unroll
                        for (int j = 0; j < 8; ++j)
                            acc[i][j] = fmaf(cf[i], d[j], acc[i][j]);
                }
            }
        }
        __syncthreads();   // protect sF/sIn for next iteration
    }

    // ---- cross-(wave,half) reduce, once per block; alias sGp onto sF ----
    {
        float* gp = sF + (t >> 5) * 1024 + (4 * cblk) * 32 + 8 * db;
#pragma unroll
        for (int i = 0; i < 4; ++i) {
            float t0[4], t1[4];
#pragma unroll
            for (int j = 0; j < 4; ++j) { t0[j] = acc[i][j]; t1[j] = acc[i][j+4]; }
            *(float4*)&gp[i * 32]     = *(float4*)t0;
            *(float4*)&gp[i * 32 + 4] = *(float4*)t1;
        }
    }
    __syncthreads();
    {
        const int e = t * 4;
        float s[4] = {0.f, 0.f, 0.f, 0.f};
#pragma unroll
        for (int w = 0; w < 8; ++w) {
            float v[4];
            *(float4*)v = *(const float4*)&sF[w * 1024 + e];
#pragma unroll
            for (int j = 0; j < 4; ++j) s[j] += v[j];
        }
        *(float4*)&partial[(size_t)blockIdx.x * 1024 + e] = *(float4*)s;
    }
}

// ---------------------------------------------------------------------------
// Kernel 2: reduce nblk partials -> NCHUNK partials (coalesced)
// ---------------------------------------------------------------------------
__global__ __launch_bounds__(256) void k_reduce(
    const float* __restrict__ partial, float* __restrict__ partial2, int nblk)
{
    const int gt    = blockIdx.x * 256 + threadIdx.x;  // 0..32767
    const int e     = gt & 1023;
    const int chunk = gt >> 10;                        // 0..31
    float s = 0.f;
    for (int b = chunk; b < nblk; b += NCHUNK) s += partial[(size_t)b * 1024 + e];
    partial2[chunk * 1024 + e] = s;
}

// ---------------------------------------------------------------------------
// Kernel 3: tail — gram finalize + conv2+BN+ReLU + conv3+BN+ReLU + mean
// 1024 threads; ALL weights staged to LDS first (the R2 bottleneck was
// ~2150 serialized per-thread global weight loads on a single CU).
// ---------------------------------------------------------------------------
__global__ __launch_bounds__(1024) void k_tail(
    const float* __restrict__ partial2,
    const float* __restrict__ w2, const float* __restrict__ b2,
    const float* __restrict__ g2, const float* __restrict__ bt2,
    const float* __restrict__ w3, const float* __restrict__ b3,
    const float* __restrict__ g3, const float* __restrict__ bt3,
    float* __restrict__ out)
{
    __shared__ float G[1024];         // 32x32 gram
    __shared__ float y1[16 * 289];    // conv2 out / h1 (17x17)
    __shared__ float y2[32 * 100];    // conv3 out (10x10)
    __shared__ float m1[16], r1[16];
    __shared__ float sw2[144], sp2[48];          // w2; {b2,g2,bt2}
    __shared__ float sw3[4608], sp3[96];         // w3; {b3,g3,bt3}

    const int t = threadIdx.x;

    // ---- stage weights to LDS (coalesced, once) ----
    for (int i = t; i < 144; i += 1024) sw2[i] = w2[i];
    for (int i = t; i < 4608; i += 1024) sw3[i] = w3[i];
    if (t < 16)              sp2[t]      = b2[t];
    else if (t < 32)         sp2[t]      = g2[t - 16];
    else if (t < 48)         sp2[t]      = bt2[t - 32];
    if (t >= 64 && t < 96)   sp3[t - 64] = b3[t - 64];
    else if (t >= 96 && t < 128)  sp3[t - 64] = g3[t - 96];
    else if (t >= 128 && t < 160) sp3[t - 64] = bt3[t - 128];

    // ---- gram finalize: one element per thread ----
    {
        float s = 0.f;
        for (int k = 0; k < NCHUNK; ++k) s += partial2[k * 1024 + t];
        G[t] = s;
    }
    __syncthreads();

    // ---- conv2: 1x32x32 -> 16x17x17, stride 2, pad 2 ----
    for (int idx = t; idx < 16 * 289; idx += 1024) {
        const int oc = idx / 289;
        const int r  = idx - oc * 289;
        const int oy = r / 17, ox = r - (r / 17) * 17;
        float s = sp2[oc];   // b2
#pragma unroll
        for (int ky = 0; ky < 3; ++ky) {
            const int iy = 2 * oy + ky - 2;
            if ((unsigned)iy >= 32u) continue;
#pragma unroll
            for (int kx = 0; kx < 3; ++kx) {
                const int ix = 2 * ox + kx - 2;
                if ((unsigned)ix >= 32u) continue;
                s = fmaf(G[iy * 32 + ix], sw2[oc * 9 + ky * 3 + kx], s);
            }
        }
        y1[idx] = s;
    }
    __syncthreads();

    // ---- BN1 stats: one wave per channel ----
    {
        const int ch = t >> 6, j = t & 63;
        float s = 0.f, ss = 0.f;
        for (int i = j; i < 289; i += 64) {
            float v = y1[ch * 289 + i];
            s += v; ss += v * v;
        }
#pragma unroll
        for (int o = 32; o; o >>= 1) { s += __shfl_xor(s, o); ss += __shfl_xor(ss, o); }
        if (j == 0) {
            float m = s * (1.f / 289.f);
            float var = ss * (1.f / 289.f) - m * m;
            m1[ch] = m;
            r1[ch] = rsqrtf(var + 1e-5f);
        }
    }
    __syncthreads();

    // ---- apply BN1 + ReLU in place ----
    for (int idx = t; idx < 16 * 289; idx += 1024) {
        const int oc = idx / 289;
        float v = (y1[idx] - m1[oc]) * r1[oc] * sp2[16 + oc] + sp2[32 + oc];
        y1[idx] = v > 0.f ? v : 0.f;
    }
    __syncthreads();

    // ---- conv3: 16x17x17 -> 32x10x10, stride 2, pad 2 ----
    for (int idx = t; idx < 3200; idx += 1024) {
        const int oc = idx / 100;
        const int r  = idx - oc * 100;
        const int oy = r / 10, ox = r - (r / 10) * 10;
        float s = sp3[oc];   // b3
        for (int ic = 0; ic < 16; ++ic) {
            const float* yi = y1 + ic * 289;
            const float* wr = sw3 + (oc * 16 + ic) * 9;
#pragma unroll
            for (int ky = 0; ky < 3; ++ky) {
                const int iy = 2 * oy + ky - 2;
                if ((unsigned)iy >= 17u) continue;
#pragma unroll
                for (int kx = 0; kx < 3; ++kx) {
                    const int ix = 2 * ox + kx - 2;
                    if ((unsigned)ix >= 17u) continue;
                    s = fmaf(yi[iy * 17 + ix], wr[ky * 3 + kx], s);
                }
            }
        }
        y2[idx] = s;
    }
    __syncthreads();

    // ---- BN2 + ReLU + spatial mean: 32 lanes per channel ----
    {
        const int ch = t >> 5, j = t & 31;
        float s = 0.f, ss = 0.f;
        for (int i = j; i < 100; i += 32) {
            float v = y2[ch * 100 + i];
            s += v; ss += v * v;
        }
#pragma unroll
        for (int o = 16; o; o >>= 1) { s += __shfl_xor(s, o); ss += __shfl_xor(ss, o); }
        const float m  = s * 0.01f;
        const float var = ss * 0.01f - m * m;
        const float rs = rsqrtf(var + 1e-5f);
        float a = 0.f;
        for (int i = j; i < 100; i += 32) {
            float v = (y2[ch * 100 + i] - m) * rs * sp3[32 + ch] + sp3[64 + ch];
            a += v > 0.f ? v : 0.f;
        }
#pragma unroll
        for (int o = 16; o; o >>= 1) a += __shfl_xor(a, o);
        if (j == 0) out[ch] = a * 0.01f;
    }
}

// ---------------------------------------------------------------------------
extern "C" void kernel_launch(void* const* d_in, const int* in_sizes, int n_in,
                              void* d_out, int out_size, void* d_ws, size_t ws_size,
                              hipStream_t stream)
{
    const float* x   = (const float*)d_in[0];
    const float* w1  = (const float*)d_in[1];
    const float* b1  = (const float*)d_in[2];
    const float* w2  = (const float*)d_in[3];
    const float* b2  = (const float*)d_in[4];
    const float* g2  = (const float*)d_in[5];
    const float* bt2 = (const float*)d_in[6];
    const float* w3  = (const float*)d_in[7];
    const float* b3  = (const float*)d_in[8];
    const float* g3  = (const float*)d_in[9];
    const float* bt3 = (const float*)d_in[10];

    // size grid from workspace: nblk partial grams (4 KB each) + NCHUNK stage-2
    size_t cap = ws_size / 4096;
    int nblk = (cap > (size_t)(NTILES + NCHUNK)) ? NTILES : (int)cap - NCHUNK;
    if (nblk > NTILES) nblk = NTILES;
    if (nblk < 256) nblk = 256;   // ws is known to hold at least this (R1 ran 1060)

    float* P   = (float*)d_ws;                 // [nblk][1024]
    float* P2  = P + (size_t)nblk * 1024;      // [NCHUNK][1024]
    float* out = (float*)d_out;                // 32 floats

    k_conv_gram<<<nblk, 256, 0, stream>>>(x, w1, b1, P, nblk);
    k_reduce<<<128, 256, 0, stream>>>(P, P2, nblk);
    k_tail<<<1, 1024, 0, stream>>>(P2, w2, b2, g2, bt2, w3, b3, g3, bt3, out);
}